// Round 1
// baseline (447.119 us; speedup 1.0000x reference)
//
#include <hip/hip_runtime.h>

#define EPSF 1e-12f

constexpr int B = 8, V = 6890, F = 13776, N = 4096;
constexpr int BF = B * F;
constexpr int BN = B * N;

// ---- block-wide sum over 256 threads (4 waves of 64) ----
__device__ __forceinline__ float block_sum_256(float v, float* s4) {
  #pragma unroll
  for (int off = 32; off > 0; off >>= 1) v += __shfl_down(v, off, 64);
  __syncthreads();                       // protect s4 from prior use
  if ((threadIdx.x & 63) == 0) s4[threadIdx.x >> 6] = v;
  __syncthreads();
  return s4[0] + s4[1] + s4[2] + s4[3];
}

__global__ void zero_kernel(float* acc) {
  if (threadIdx.x < 4) acc[threadIdx.x] = 0.f;
}

// Per (b,f): area, unit normal, edge-length^2 sum (accumulated to acc[3]).
__global__ void face_kernel(const float* __restrict__ pv, const int* __restrict__ pf,
                            float* __restrict__ area, float* __restrict__ nrm,
                            float* __restrict__ acc) {
  __shared__ float s4[4];
  int idx = blockIdx.x * 256 + threadIdx.x;
  float es = 0.f;
  if (idx < BF) {
    int b = idx / F, f = idx - b * F;
    int i0 = pf[f * 3 + 0], i1 = pf[f * 3 + 1], i2 = pf[f * 3 + 2];
    const float* vb = pv + (size_t)b * V * 3;
    float x0 = vb[i0 * 3 + 0], y0 = vb[i0 * 3 + 1], z0 = vb[i0 * 3 + 2];
    float x1 = vb[i1 * 3 + 0], y1 = vb[i1 * 3 + 1], z1 = vb[i1 * 3 + 2];
    float x2 = vb[i2 * 3 + 0], y2 = vb[i2 * 3 + 1], z2 = vb[i2 * 3 + 2];
    float ax = x1 - x0, ay = y1 - y0, az = z1 - z0;   // v1-v0
    float bx = x2 - x0, by = y2 - y0, bz = z2 - z0;   // v2-v0
    float cx = ay * bz - az * by;
    float cy = az * bx - ax * bz;
    float cz = ax * by - ay * bx;
    float cn = sqrtf(cx * cx + cy * cy + cz * cz);
    area[idx] = 0.5f * cn;
    float inv = 1.f / (cn + EPSF);
    nrm[(size_t)idx * 3 + 0] = cx * inv;
    nrm[(size_t)idx * 3 + 1] = cy * inv;
    nrm[(size_t)idx * 3 + 2] = cz * inv;
    // edges: e01 = v0-v1, e12 = v1-v2, e20 = v2-v0 (= b)
    float ex = x0 - x1, ey = y0 - y1, ez = z0 - z1;
    es = ex * ex + ey * ey + ez * ez;
    ex = x1 - x2; ey = y1 - y2; ez = z1 - z2;
    es += ex * ex + ey * ey + ez * ez;
    es += bx * bx + by * by + bz * bz;
  }
  float tot = block_sum_256(es, s4);
  if (threadIdx.x == 0) atomicAdd(&acc[3], tot);
}

// In-place inclusive cumsum over F per batch; one block per batch.
__global__ void scan_kernel(float* __restrict__ cdf, float* __restrict__ totals) {
  int b = blockIdx.x;
  float* c = cdf + (size_t)b * F;
  __shared__ float lds[256];
  float carry = 0.f;
  for (int base = 0; base < F; base += 256) {
    int i = base + threadIdx.x;
    float v = (i < F) ? c[i] : 0.f;
    lds[threadIdx.x] = v;
    __syncthreads();
    #pragma unroll
    for (int off = 1; off < 256; off <<= 1) {
      float t = (threadIdx.x >= off) ? lds[threadIdx.x - off] : 0.f;
      __syncthreads();
      lds[threadIdx.x] += t;
      __syncthreads();
    }
    if (i < F) c[i] = lds[threadIdx.x] + carry;
    carry += lds[255];
    __syncthreads();   // before next chunk overwrites lds
  }
  if (threadIdx.x == 0) totals[b] = carry;
}

// Sample 2*B*N surface points: binary search CDF, barycentric combine, gather normal.
__global__ void sample_kernel(const float* __restrict__ pv, const int* __restrict__ pf,
                              const float* __restrict__ cdf, const float* __restrict__ totals,
                              const float* __restrict__ nrm,
                              const float* __restrict__ rp, const float* __restrict__ rg,
                              float* __restrict__ pc, float* __restrict__ pn,
                              float* __restrict__ gc, float* __restrict__ gn) {
  int idx = blockIdx.x * 256 + threadIdx.x;
  if (idx >= 2 * BN) return;
  int set = (idx >= BN) ? 1 : 0;
  int i = idx - set * BN;           // [0, BN)
  int b = i / N;
  const float* r = (set ? rg : rp) + (size_t)i * 3;
  float u = r[0], r1 = r[1], r2 = r[2];
  float target = u * (totals[b] + EPSF);
  const float* c = cdf + (size_t)b * F;
  int lo = 0, hi = F;               // searchsorted(side='left'): first c[i] >= target
  while (lo < hi) {
    int mid = (lo + hi) >> 1;
    if (c[mid] < target) lo = mid + 1; else hi = mid;
  }
  int f = lo < F ? lo : F - 1;      // clip
  int i0 = pf[f * 3 + 0], i1 = pf[f * 3 + 1], i2 = pf[f * 3 + 2];
  const float* vb = pv + (size_t)b * V * 3;
  float su = sqrtf(r1);
  float w0 = 1.f - su, w1 = su * (1.f - r2), w2 = su * r2;
  float px = w0 * vb[i0 * 3 + 0] + w1 * vb[i1 * 3 + 0] + w2 * vb[i2 * 3 + 0];
  float py = w0 * vb[i0 * 3 + 1] + w1 * vb[i1 * 3 + 1] + w2 * vb[i2 * 3 + 1];
  float pz = w0 * vb[i0 * 3 + 2] + w1 * vb[i1 * 3 + 2] + w2 * vb[i2 * 3 + 2];
  float* pts = (set ? gc : pc) + (size_t)i * 3;
  float* pns = (set ? gn : pn) + (size_t)i * 3;
  pts[0] = px; pts[1] = py; pts[2] = pz;
  size_t nb = ((size_t)b * F + f) * 3;
  pns[0] = nrm[nb + 0]; pns[1] = nrm[nb + 1]; pns[2] = nrm[nb + 2];
}

// Fused chamfer: blocks [0,128) = dist1+argmin+normal loss (thread per n),
//                blocks [128,256) = dist2 (thread per m).
__global__ __launch_bounds__(256) void chamfer_kernel(
    const float* __restrict__ pc, const float* __restrict__ pn,
    const float* __restrict__ gc, const float* __restrict__ gn,
    float* __restrict__ acc) {
  __shared__ float4 tile[256];
  __shared__ float s4[4];
  bool is1 = blockIdx.x < 128;
  int blk = is1 ? blockIdx.x : blockIdx.x - 128;
  int b = blk >> 4;                       // / (N/256=16)
  int n = ((blk & 15) << 8) + threadIdx.x;
  const float* own   = (is1 ? pc : gc) + ((size_t)b * N + n) * 3;
  const float* other = is1 ? gc : pc;
  float px = own[0], py = own[1], pz = own[2];
  float best = 3.4e38f;
  int bestm = 0;
  for (int mb = 0; mb < N; mb += 256) {
    const float* g = other + ((size_t)b * N + mb + threadIdx.x) * 3;
    __syncthreads();
    tile[threadIdx.x] = make_float4(g[0], g[1], g[2], 0.f);
    __syncthreads();
    if (is1) {
      #pragma unroll 16
      for (int j = 0; j < 256; ++j) {
        float4 t = tile[j];
        float dx = px - t.x, dy = py - t.y, dz = pz - t.z;
        float d = dx * dx + dy * dy + dz * dz;
        if (d < best) { best = d; bestm = mb + j; }  // strict <: first occurrence
      }
    } else {
      #pragma unroll 16
      for (int j = 0; j < 256; ++j) {
        float4 t = tile[j];
        float dx = px - t.x, dy = py - t.y, dz = pz - t.z;
        float d = dx * dx + dy * dy + dz * dz;
        best = fminf(best, d);
      }
    }
  }
  float nl = 0.f;
  if (is1) {
    const float* a  = pn + ((size_t)b * N + n) * 3;
    const float* bb = gn + ((size_t)b * N + bestm) * 3;
    nl = 1.f - fabsf(a[0] * bb[0] + a[1] * bb[1] + a[2] * bb[2]);
  }
  float sd = block_sum_256(best, s4);
  float sn = block_sum_256(nl, s4);
  if (threadIdx.x == 0) {
    atomicAdd(&acc[is1 ? 0 : 1], sd);
    if (is1) atomicAdd(&acc[2], sn);
  }
}

__global__ void final_kernel(const float* __restrict__ acc, float* __restrict__ out) {
  if (threadIdx.x == 0 && blockIdx.x == 0) {
    float inv_bn = 1.f / (float)BN;
    float chamfer = (acc[0] + acc[1]) * inv_bn;
    float nrm_l = acc[2] * inv_bn;
    float edge = acc[3] / (3.f * (float)BF);
    out[0] = 1.0f * chamfer + 0.1f * nrm_l + 0.5f * edge;
  }
}

extern "C" void kernel_launch(void* const* d_in, const int* in_sizes, int n_in,
                              void* d_out, int out_size, void* d_ws, size_t ws_size,
                              hipStream_t stream) {
  const float* pv = (const float*)d_in[0];   // predicted_vertices [B,V,3]
  const int*   pf = (const int*)d_in[1];     // predicted_faces [F,3]
  // d_in[2] (gt_vertices) and d_in[3] (gt_faces) are unused by the reference.
  const float* rp = (const float*)d_in[4];   // rand_pred [B,N,3]
  const float* rg = (const float*)d_in[5];   // rand_gt   [B,N,3]
  float* out = (float*)d_out;

  float* ws = (float*)d_ws;
  float* cdf    = ws;                          // BF (area, scanned in-place)
  float* nrm    = cdf + BF;                    // BF*3
  float* pc     = nrm + (size_t)BF * 3;        // BN*3
  float* pn     = pc + (size_t)BN * 3;         // BN*3
  float* gc     = pn + (size_t)BN * 3;         // BN*3
  float* gn     = gc + (size_t)BN * 3;         // BN*3
  float* totals = gn + (size_t)BN * 3;         // B
  float* acc    = totals + B;                  // 4

  zero_kernel<<<1, 64, 0, stream>>>(acc);
  face_kernel<<<(BF + 255) / 256, 256, 0, stream>>>(pv, pf, cdf, nrm, acc);
  scan_kernel<<<B, 256, 0, stream>>>(cdf, totals);
  sample_kernel<<<(2 * BN) / 256, 256, 0, stream>>>(pv, pf, cdf, totals, nrm,
                                                    rp, rg, pc, pn, gc, gn);
  chamfer_kernel<<<256, 256, 0, stream>>>(pc, pn, gc, gn, acc);
  final_kernel<<<1, 64, 0, stream>>>(acc, out);
}

// Round 2
// 131.191 us; speedup vs baseline: 3.4081x; 3.4081x over previous
//
#include <hip/hip_runtime.h>

#define EPSF 1e-12f
#define FLTMAX 3.402823466e+38f

constexpr int B = 8, V = 6890, F = 13776, N = 4096;
constexpr int BF = B * F;
constexpr int BN = B * N;
constexpr int CHUNK = 512;
constexpr int NCHUNK = (F + CHUNK - 1) / CHUNK;   // 27

// Order-preserving float <-> uint encode (total order incl. negatives).
__device__ __forceinline__ unsigned enc_f(float f) {
  unsigned b = __float_as_uint(f);
  return (b & 0x80000000u) ? ~b : (b | 0x80000000u);
}
__device__ __forceinline__ float dec_f(unsigned u) {
  return (u & 0x80000000u) ? __uint_as_float(u & 0x7FFFFFFFu) : __uint_as_float(~u);
}

// ---- block-wide sum over 256 threads (4 waves of 64) ----
__device__ __forceinline__ float block_sum_256(float v, float* s4) {
  #pragma unroll
  for (int off = 32; off > 0; off >>= 1) v += __shfl_down(v, off, 64);
  __syncthreads();
  if ((threadIdx.x & 63) == 0) s4[threadIdx.x >> 6] = v;
  __syncthreads();
  return s4[0] + s4[1] + s4[2] + s4[3];
}

// Init: best1 = u64 max, best2 = u32 max, acc = 0.  Grid: BN/256 = 128 blocks.
__global__ void init_kernel(unsigned long long* __restrict__ best1,
                            unsigned* __restrict__ best2, float* __restrict__ acc) {
  int i = blockIdx.x * 256 + threadIdx.x;
  best1[i] = ~0ull;
  best2[i] = ~0u;
  if (i < 4) acc[i] = 0.f;
}

// Per (b,f): area (into cdf slot), unit normal, edge-length^2 sum -> acc[3].
__global__ void face_kernel(const float* __restrict__ pv, const int* __restrict__ pf,
                            float* __restrict__ area, float* __restrict__ nrm,
                            float* __restrict__ acc) {
  __shared__ float s4[4];
  int idx = blockIdx.x * 256 + threadIdx.x;
  float es = 0.f;
  if (idx < BF) {
    int b = idx / F, f = idx - b * F;
    int i0 = pf[f * 3 + 0], i1 = pf[f * 3 + 1], i2 = pf[f * 3 + 2];
    const float* vb = pv + (size_t)b * V * 3;
    float x0 = vb[i0 * 3 + 0], y0 = vb[i0 * 3 + 1], z0 = vb[i0 * 3 + 2];
    float x1 = vb[i1 * 3 + 0], y1 = vb[i1 * 3 + 1], z1 = vb[i1 * 3 + 2];
    float x2 = vb[i2 * 3 + 0], y2 = vb[i2 * 3 + 1], z2 = vb[i2 * 3 + 2];
    float ax = x1 - x0, ay = y1 - y0, az = z1 - z0;
    float bx = x2 - x0, by = y2 - y0, bz = z2 - z0;
    float cx = ay * bz - az * by;
    float cy = az * bx - ax * bz;
    float cz = ax * by - ay * bx;
    float cn = sqrtf(cx * cx + cy * cy + cz * cz);
    area[idx] = 0.5f * cn;
    float inv = 1.f / (cn + EPSF);
    nrm[(size_t)idx * 3 + 0] = cx * inv;
    nrm[(size_t)idx * 3 + 1] = cy * inv;
    nrm[(size_t)idx * 3 + 2] = cz * inv;
    float ex = x0 - x1, ey = y0 - y1, ez = z0 - z1;
    es = ex * ex + ey * ey + ez * ez;
    ex = x1 - x2; ey = y1 - y2; ez = z1 - z2;
    es += ex * ex + ey * ey + ez * ez;
    es += bx * bx + by * by + bz * bz;
  }
  float tot = block_sum_256(es, s4);
  if (threadIdx.x == 0) atomicAdd(&acc[3], tot);
}

// Phase A: per-chunk inclusive scan (512 elems / block, 2 per thread, wave shuffles).
// Writes chunk-local scanned values in place; chunk totals -> csum[b][ck].
__global__ void scan_chunks(float* __restrict__ cdf, float* __restrict__ csum) {
  int b = blockIdx.x / NCHUNK, ck = blockIdx.x % NCHUNK;
  float* c = cdf + (size_t)b * F;
  int lane = threadIdx.x & 63, wid = threadIdx.x >> 6;
  int i0 = ck * CHUNK + 2 * threadIdx.x, i1 = i0 + 1;
  float a0 = (i0 < F) ? c[i0] : 0.f;
  float a1 = (i1 < F) ? c[i1] : 0.f;
  float ts = a0 + a1;
  float x = ts;
  #pragma unroll
  for (int off = 1; off < 64; off <<= 1) {
    float y = __shfl_up(x, off, 64);
    if (lane >= off) x += y;
  }
  __shared__ float wsum[4];
  if (lane == 63) wsum[wid] = x;
  __syncthreads();
  float woff = 0.f;
  for (int w = 0; w < wid; ++w) woff += wsum[w];
  float excl = woff + x - ts;
  if (i0 < F) c[i0] = excl + a0;
  if (i1 < F) c[i1] = excl + ts;
  if (threadIdx.x == 255) csum[b * NCHUNK + ck] = woff + x;   // chunk total
}

// Phase B: inclusive scan of 27 chunk totals per batch; totals[b] = grand total.
__global__ void scan_sums(float* __restrict__ csum, float* __restrict__ totals) {
  int b = threadIdx.x;
  if (b < B) {
    float s = 0.f;
    for (int k = 0; k < NCHUNK; ++k) { s += csum[b * NCHUNK + k]; csum[b * NCHUNK + k] = s; }
    totals[b] = s;
  }
}

// Sample 2*B*N points: two-level search (chunk sums, then within-chunk), barycentric.
__global__ void sample_kernel(const float* __restrict__ pv, const int* __restrict__ pf,
                              const float* __restrict__ cdf, const float* __restrict__ csum,
                              const float* __restrict__ totals, const float* __restrict__ nrm,
                              const float* __restrict__ rp, const float* __restrict__ rg,
                              float* __restrict__ pc, float* __restrict__ pn,
                              float* __restrict__ gc, float* __restrict__ gn) {
  int idx = blockIdx.x * 256 + threadIdx.x;
  if (idx >= 2 * BN) return;
  int set = (idx >= BN) ? 1 : 0;
  int i = idx - set * BN;
  int b = i / N;
  const float* r = (set ? rg : rp) + (size_t)i * 3;
  float u = r[0], r1 = r[1], r2 = r[2];
  float target = u * (totals[b] + EPSF);
  const float* cs = csum + b * NCHUNK;
  int lo = 0, hi = NCHUNK;                  // first k with cs[k] >= target
  while (lo < hi) { int mid = (lo + hi) >> 1; if (cs[mid] < target) lo = mid + 1; else hi = mid; }
  int k = lo < NCHUNK ? lo : NCHUNK - 1;
  float off = (k > 0) ? cs[k - 1] : 0.f;
  float t2 = target - off;
  const float* c = cdf + (size_t)b * F;
  int base = k * CHUNK;
  int lo2 = 0, hi2 = CHUNK;                 // first j with local[j] >= t2
  while (lo2 < hi2) {
    int mid = (lo2 + hi2) >> 1;
    int gi = base + mid;
    float v = (gi < F) ? c[gi] : FLTMAX;
    if (v < t2) lo2 = mid + 1; else hi2 = mid;
  }
  int f = base + lo2;
  if (f > F - 1) f = F - 1;
  int i0 = pf[f * 3 + 0], i1 = pf[f * 3 + 1], i2 = pf[f * 3 + 2];
  const float* vb = pv + (size_t)b * V * 3;
  float su = sqrtf(r1);
  float w0 = 1.f - su, w1 = su * (1.f - r2), w2 = su * r2;
  float px = w0 * vb[i0 * 3 + 0] + w1 * vb[i1 * 3 + 0] + w2 * vb[i2 * 3 + 0];
  float py = w0 * vb[i0 * 3 + 1] + w1 * vb[i1 * 3 + 1] + w2 * vb[i2 * 3 + 1];
  float pz = w0 * vb[i0 * 3 + 2] + w1 * vb[i1 * 3 + 2] + w2 * vb[i2 * 3 + 2];
  float* pts = (set ? gc : pc) + (size_t)i * 3;
  float* pns = (set ? gn : pn) + (size_t)i * 3;
  pts[0] = px; pts[1] = py; pts[2] = pz;
  size_t nb = ((size_t)b * F + f) * 3;
  pns[0] = nrm[nb + 0]; pns[1] = nrm[nb + 1]; pns[2] = nrm[nb + 2];
}

// Chamfer, split-m: 2048 blocks. [0,1024) dist1 (thread per n, argmin kept),
// [1024,2048) dist2 (thread per m). Each block scans 512 points of the other set.
// Partial results merged via atomicMin on order-preserving encoded keys.
__global__ __launch_bounds__(256, 4) void chamfer_kernel(
    const float* __restrict__ pc, const float* __restrict__ gc,
    unsigned long long* __restrict__ best1, unsigned* __restrict__ best2) {
  __shared__ float4 tile[256];
  bool is1 = blockIdx.x < 1024;
  int blk = is1 ? blockIdx.x : blockIdx.x - 1024;
  int b = blk >> 7;                  // 128 blocks/batch = 16 nchunks * 8 mchunks
  int nchunk = (blk >> 3) & 15, mchunk = blk & 7;
  int n = nchunk * 256 + threadIdx.x;
  int mbase = mchunk * 512;
  const float* own   = (is1 ? pc : gc) + ((size_t)b * N + n) * 3;
  const float* other = (is1 ? gc : pc) + (size_t)b * N * 3;
  float px = own[0], py = own[1], pz = own[2];
  float pp = px * px + py * py + pz * pz;
  float qx = -2.f * px, qy = -2.f * py, qz = -2.f * pz;
  float bd0 = FLTMAX, bd1 = FLTMAX, bd2 = FLTMAX, bd3 = FLTMAX;
  int bi0 = 0, bi1 = 0, bi2 = 0, bi3 = 0;
  for (int stage = 0; stage < 2; ++stage) {
    int mb = mbase + stage * 256;
    const float* g = other + (size_t)(mb + threadIdx.x) * 3;
    float gx = g[0], gy = g[1], gz = g[2];
    __syncthreads();
    tile[threadIdx.x] = make_float4(gx, gy, gz, gx * gx + gy * gy + gz * gz);
    __syncthreads();
    if (is1) {
      #pragma unroll 4
      for (int k = 0; k < 64; ++k) {
        int j = 4 * k;
        float4 t0 = tile[j], t1 = tile[j + 1], t2 = tile[j + 2], t3 = tile[j + 3];
        float d0 = fmaf(qx, t0.x, fmaf(qy, t0.y, fmaf(qz, t0.z, pp + t0.w)));
        float d1 = fmaf(qx, t1.x, fmaf(qy, t1.y, fmaf(qz, t1.z, pp + t1.w)));
        float d2 = fmaf(qx, t2.x, fmaf(qy, t2.y, fmaf(qz, t2.z, pp + t2.w)));
        float d3 = fmaf(qx, t3.x, fmaf(qy, t3.y, fmaf(qz, t3.z, pp + t3.w)));
        if (d0 < bd0) { bd0 = d0; bi0 = mb + j; }
        if (d1 < bd1) { bd1 = d1; bi1 = mb + j + 1; }
        if (d2 < bd2) { bd2 = d2; bi2 = mb + j + 2; }
        if (d3 < bd3) { bd3 = d3; bi3 = mb + j + 3; }
      }
    } else {
      #pragma unroll 4
      for (int k = 0; k < 64; ++k) {
        int j = 4 * k;
        float4 t0 = tile[j], t1 = tile[j + 1], t2 = tile[j + 2], t3 = tile[j + 3];
        float d0 = fmaf(qx, t0.x, fmaf(qy, t0.y, fmaf(qz, t0.z, pp + t0.w)));
        float d1 = fmaf(qx, t1.x, fmaf(qy, t1.y, fmaf(qz, t1.z, pp + t1.w)));
        float d2 = fmaf(qx, t2.x, fmaf(qy, t2.y, fmaf(qz, t2.z, pp + t2.w)));
        float d3 = fmaf(qx, t3.x, fmaf(qy, t3.y, fmaf(qz, t3.z, pp + t3.w)));
        bd0 = fminf(bd0, d0); bd1 = fminf(bd1, d1);
        bd2 = fminf(bd2, d2); bd3 = fminf(bd3, d3);
      }
    }
  }
  if (is1) {
    // exact first-occurrence merge across the 4 chains
    if (bd1 < bd0 || (bd1 == bd0 && bi1 < bi0)) { bd0 = bd1; bi0 = bi1; }
    if (bd3 < bd2 || (bd3 == bd2 && bi3 < bi2)) { bd2 = bd3; bi2 = bi3; }
    if (bd2 < bd0 || (bd2 == bd0 && bi2 < bi0)) { bd0 = bd2; bi0 = bi2; }
    unsigned long long key = ((unsigned long long)enc_f(bd0) << 32) | (unsigned)bi0;
    atomicMin(&best1[(size_t)b * N + n], key);
  } else {
    bd0 = fminf(fminf(bd0, bd1), fminf(bd2, bd3));
    atomicMin(&best2[(size_t)b * N + n], enc_f(bd0));
  }
}

// Per-n: unpack best key, normal loss via argmin index; reduce 3 sums.
__global__ void finalize_kernel(const unsigned long long* __restrict__ best1,
                                const unsigned* __restrict__ best2,
                                const float* __restrict__ pn, const float* __restrict__ gn,
                                float* __restrict__ acc) {
  __shared__ float s4[4];
  int i = blockIdx.x * 256 + threadIdx.x;
  int b = i >> 12;                       // / N
  unsigned long long k1 = best1[i];
  float d1 = dec_f((unsigned)(k1 >> 32));
  int m = (int)(unsigned)(k1 & 0xFFFFFFFFull);
  float d2 = dec_f(best2[i]);
  const float* a  = pn + (size_t)i * 3;
  const float* bb = gn + ((size_t)b * N + m) * 3;
  float nl = 1.f - fabsf(a[0] * bb[0] + a[1] * bb[1] + a[2] * bb[2]);
  float sd1 = block_sum_256(d1, s4);
  float sd2 = block_sum_256(d2, s4);
  float snl = block_sum_256(nl, s4);
  if (threadIdx.x == 0) {
    atomicAdd(&acc[0], sd1);
    atomicAdd(&acc[1], sd2);
    atomicAdd(&acc[2], snl);
  }
}

__global__ void final_kernel(const float* __restrict__ acc, float* __restrict__ out) {
  if (threadIdx.x == 0 && blockIdx.x == 0) {
    float inv_bn = 1.f / (float)BN;
    float chamfer = (acc[0] + acc[1]) * inv_bn;
    float nrm_l = acc[2] * inv_bn;
    float edge = acc[3] / (3.f * (float)BF);
    out[0] = 1.0f * chamfer + 0.1f * nrm_l + 0.5f * edge;
  }
}

extern "C" void kernel_launch(void* const* d_in, const int* in_sizes, int n_in,
                              void* d_out, int out_size, void* d_ws, size_t ws_size,
                              hipStream_t stream) {
  const float* pv = (const float*)d_in[0];   // predicted_vertices [B,V,3]
  const int*   pf = (const int*)d_in[1];     // predicted_faces [F,3]
  // d_in[2]/d_in[3] (gt mesh) are unused by the reference.
  const float* rp = (const float*)d_in[4];   // rand_pred [B,N,3]
  const float* rg = (const float*)d_in[5];   // rand_gt   [B,N,3]
  float* out = (float*)d_out;

  // ws layout: 8-byte-aligned best1 first.
  unsigned long long* best1 = (unsigned long long*)d_ws;          // BN u64
  unsigned* best2 = (unsigned*)(best1 + BN);                      // BN u32
  float* fws    = (float*)(best2 + BN);
  float* cdf    = fws;                          // BF   (area -> chunk-scanned)
  float* nrm    = cdf + BF;                     // BF*3
  float* pc     = nrm + (size_t)BF * 3;         // BN*3
  float* pn     = pc + (size_t)BN * 3;          // BN*3
  float* gc     = pn + (size_t)BN * 3;          // BN*3
  float* gn     = gc + (size_t)BN * 3;          // BN*3
  float* csum   = gn + (size_t)BN * 3;          // B*NCHUNK
  float* totals = csum + B * NCHUNK;            // B
  float* acc    = totals + B;                   // 4

  init_kernel<<<BN / 256, 256, 0, stream>>>(best1, best2, acc);
  face_kernel<<<(BF + 255) / 256, 256, 0, stream>>>(pv, pf, cdf, nrm, acc);
  scan_chunks<<<B * NCHUNK, 256, 0, stream>>>(cdf, csum);
  scan_sums<<<1, 64, 0, stream>>>(csum, totals);
  sample_kernel<<<(2 * BN) / 256, 256, 0, stream>>>(pv, pf, cdf, csum, totals, nrm,
                                                    rp, rg, pc, pn, gc, gn);
  chamfer_kernel<<<2048, 256, 0, stream>>>(pc, gc, best1, best2);
  finalize_kernel<<<BN / 256, 256, 0, stream>>>(best1, best2, pn, gn, acc);
  final_kernel<<<1, 64, 0, stream>>>(acc, out);
}

// Round 3
// 125.521 us; speedup vs baseline: 3.5621x; 1.0452x over previous
//
#include <hip/hip_runtime.h>

#define EPSF 1e-12f
#define FLTMAX 3.402823466e+38f

constexpr int B = 8, V = 6890, F = 13776, N = 4096;
constexpr int BF = B * F;
constexpr int BN = B * N;
constexpr int CHUNK = 512;
constexpr int NCHUNK = (F + CHUNK - 1) / CHUNK;   // 27
constexpr int SCAN_BLOCKS = B * NCHUNK;           // 216 (also edge-partial count)

// Order-preserving float <-> uint encode (total order incl. negatives).
__device__ __forceinline__ unsigned enc_f(float f) {
  unsigned b = __float_as_uint(f);
  return (b & 0x80000000u) ? ~b : (b | 0x80000000u);
}
__device__ __forceinline__ float dec_f(unsigned u) {
  return (u & 0x80000000u) ? __uint_as_float(u & 0x7FFFFFFFu) : __uint_as_float(~u);
}

// ---- block-wide sum over 256 threads (4 waves of 64) ----
__device__ __forceinline__ float block_sum_256(float v, float* s4) {
  #pragma unroll
  for (int off = 32; off > 0; off >>= 1) v += __shfl_down(v, off, 64);
  __syncthreads();
  if ((threadIdx.x & 63) == 0) s4[threadIdx.x >> 6] = v;
  __syncthreads();
  return s4[0] + s4[1] + s4[2] + s4[3];
}

// Per-face geometry. Returns area; writes unit normal; accumulates edge-len^2 sum.
__device__ __forceinline__ float face_geom(const float* __restrict__ pv,
                                           const int* __restrict__ pf,
                                           int b, int f, float4* __restrict__ nrm4,
                                           float& es) {
  if (f >= F) return 0.f;
  int i0 = pf[f * 3 + 0], i1 = pf[f * 3 + 1], i2 = pf[f * 3 + 2];
  const float* vb = pv + (size_t)b * V * 3;
  float x0 = vb[i0 * 3 + 0], y0 = vb[i0 * 3 + 1], z0 = vb[i0 * 3 + 2];
  float x1 = vb[i1 * 3 + 0], y1 = vb[i1 * 3 + 1], z1 = vb[i1 * 3 + 2];
  float x2 = vb[i2 * 3 + 0], y2 = vb[i2 * 3 + 1], z2 = vb[i2 * 3 + 2];
  float ax = x1 - x0, ay = y1 - y0, az = z1 - z0;
  float bx = x2 - x0, by = y2 - y0, bz = z2 - z0;
  float cx = ay * bz - az * by;
  float cy = az * bx - ax * bz;
  float cz = ax * by - ay * bx;
  float cn = sqrtf(cx * cx + cy * cy + cz * cz);
  float inv = 1.f / (cn + EPSF);
  nrm4[(size_t)b * F + f] = make_float4(cx * inv, cy * inv, cz * inv, 0.f);
  float ex = x0 - x1, ey = y0 - y1, ez = z0 - z1;
  es += ex * ex + ey * ey + ez * ez;
  ex = x1 - x2; ey = y1 - y2; ez = z1 - z2;
  es += ex * ex + ey * ey + ez * ez;
  es += bx * bx + by * by + bz * bz;
  return 0.5f * cn;
}

// K1: fused face-geometry + per-chunk scan + init. One block per (b, chunk).
// Each thread computes 2 consecutive faces' areas in-register, then the block
// scans them (same fp association as a load-then-scan). Also: init best1/best2,
// zero acc/cnt, per-block edge partial.
__global__ __launch_bounds__(256) void scan_faces_kernel(
    const float* __restrict__ pv, const int* __restrict__ pf,
    float* __restrict__ cdf, float* __restrict__ csum, float4* __restrict__ nrm4,
    float* __restrict__ edgep,
    unsigned long long* __restrict__ best1, unsigned* __restrict__ best2,
    float* __restrict__ acc, unsigned* __restrict__ cnt) {
  __shared__ float wsum[4];
  __shared__ float s4[4];
  int b = blockIdx.x / NCHUNK, ck = blockIdx.x % NCHUNK;
  int lane = threadIdx.x & 63, wid = threadIdx.x >> 6;

  int gid = blockIdx.x * 256 + threadIdx.x;
  if (gid < BN) { best1[gid] = ~0ull; best2[gid] = ~0u; }
  if (gid < 2) acc[gid] = 0.f;
  if (gid == 2) *cnt = 0u;

  int f0 = ck * CHUNK + 2 * threadIdx.x;
  float es = 0.f;
  float a0 = face_geom(pv, pf, b, f0, nrm4, es);
  float a1 = face_geom(pv, pf, b, f0 + 1, nrm4, es);

  float ts = a0 + a1;
  float x = ts;
  #pragma unroll
  for (int off = 1; off < 64; off <<= 1) {
    float y = __shfl_up(x, off, 64);
    if (lane >= off) x += y;
  }
  if (lane == 63) wsum[wid] = x;
  __syncthreads();
  float woff = 0.f;
  for (int w = 0; w < wid; ++w) woff += wsum[w];
  float excl = woff + x - ts;
  size_t g0 = (size_t)b * F + f0;
  if (f0 < F) cdf[g0] = excl + a0;
  if (f0 + 1 < F) cdf[g0 + 1] = excl + ts;
  if (threadIdx.x == 255) csum[blockIdx.x] = woff + x;   // chunk total (raw)

  float te = block_sum_256(es, s4);
  if (threadIdx.x == 0) edgep[blockIdx.x] = te;
}

// K2: sample 2*B*N points. On-the-fly scan of 27 raw chunk totals (L1-hot),
// then in-chunk binary search. Writes float4 (x,y,z,|p|^2) + float4 normal.
__global__ __launch_bounds__(256) void sample_kernel(
    const float* __restrict__ pv, const int* __restrict__ pf,
    const float* __restrict__ cdf, const float* __restrict__ csum,
    const float4* __restrict__ nrm4,
    const float* __restrict__ rp, const float* __restrict__ rg,
    float4* __restrict__ pc4, float4* __restrict__ pn4,
    float4* __restrict__ gc4, float4* __restrict__ gn4) {
  int idx = blockIdx.x * 256 + threadIdx.x;
  if (idx >= 2 * BN) return;
  int set = (idx >= BN) ? 1 : 0;
  int i = idx - set * BN;
  int b = i / N;
  const float* r = (set ? rg : rp) + (size_t)i * 3;
  float u = r[0], r1 = r[1], r2 = r[2];

  const float* cs = csum + b * NCHUNK;
  float total = 0.f;
  #pragma unroll
  for (int k2 = 0; k2 < NCHUNK; ++k2) total += cs[k2];
  float target = u * (total + EPSF);

  int k = 0;
  float s = cs[0];
  while (s < target && k < NCHUNK - 1) { ++k; s += cs[k]; }
  float prefix = s - cs[k];
  float t2 = target - prefix;

  const float* c = cdf + (size_t)b * F + k * CHUNK;
  int base = k * CHUNK;
  int lo = 0, hi = CHUNK;                 // first j with chunk-local scanned >= t2
  while (lo < hi) {
    int mid = (lo + hi) >> 1;
    float v = (base + mid < F) ? c[mid] : FLTMAX;
    if (v < t2) lo = mid + 1; else hi = mid;
  }
  int f = base + lo;
  if (f > F - 1) f = F - 1;

  int i0 = pf[f * 3 + 0], i1 = pf[f * 3 + 1], i2 = pf[f * 3 + 2];
  const float* vb = pv + (size_t)b * V * 3;
  float su = sqrtf(r1);
  float w0 = 1.f - su, w1 = su * (1.f - r2), w2 = su * r2;
  float px = w0 * vb[i0 * 3 + 0] + w1 * vb[i1 * 3 + 0] + w2 * vb[i2 * 3 + 0];
  float py = w0 * vb[i0 * 3 + 1] + w1 * vb[i1 * 3 + 1] + w2 * vb[i2 * 3 + 1];
  float pz = w0 * vb[i0 * 3 + 2] + w1 * vb[i1 * 3 + 2] + w2 * vb[i2 * 3 + 2];
  float4* pts = (set ? gc4 : pc4);
  float4* pns = (set ? gn4 : pn4);
  pts[i] = make_float4(px, py, pz, px * px + py * py + pz * pz);
  pns[i] = nrm4[(size_t)b * F + f];
}

// K3: chamfer, LDS-free. Blocks [0,1024): dist1+argmin (thread per pc-row);
// [1024,2048): dist2 (thread per gc-row). The m-stream is read via wave-uniform
// float4 loads (x,y,z,|g|^2) -> expected s_load + SGPR-fed FMAs.
__global__ __launch_bounds__(256, 8) void chamfer_kernel(
    const float4* __restrict__ pc4, const float4* __restrict__ gc4,
    unsigned long long* __restrict__ best1, unsigned* __restrict__ best2) {
  const bool is1 = blockIdx.x < 1024;
  const int blk = is1 ? blockIdx.x : blockIdx.x - 1024;
  const int b = blk >> 7;                 // 128 blocks/batch = 16 nchunks * 8 mchunks
  const int nchunk = (blk >> 3) & 15, mchunk = blk & 7;
  const int n = nchunk * 256 + threadIdx.x;
  const int mbase = mchunk * 512;
  const float4 p = (is1 ? pc4 : gc4)[(size_t)b * N + n];
  const float4* __restrict__ other = (is1 ? gc4 : pc4) + (size_t)b * N + mbase;
  const float qx = -2.f * p.x, qy = -2.f * p.y, qz = -2.f * p.z;
  const float pp = p.w;

  if (is1) {
    float bd0 = FLTMAX, bd1 = FLTMAX, bd2 = FLTMAX, bd3 = FLTMAX;
    int bi0 = 0, bi1 = 0, bi2 = 0, bi3 = 0;
    #pragma unroll 2
    for (int j = 0; j < 512; j += 4) {
      float4 t0 = other[j], t1 = other[j + 1], t2 = other[j + 2], t3 = other[j + 3];
      float d0 = fmaf(qx, t0.x, fmaf(qy, t0.y, fmaf(qz, t0.z, pp + t0.w)));
      float d1 = fmaf(qx, t1.x, fmaf(qy, t1.y, fmaf(qz, t1.z, pp + t1.w)));
      float d2 = fmaf(qx, t2.x, fmaf(qy, t2.y, fmaf(qz, t2.z, pp + t2.w)));
      float d3 = fmaf(qx, t3.x, fmaf(qy, t3.y, fmaf(qz, t3.z, pp + t3.w)));
      if (d0 < bd0) { bd0 = d0; bi0 = mbase + j; }
      if (d1 < bd1) { bd1 = d1; bi1 = mbase + j + 1; }
      if (d2 < bd2) { bd2 = d2; bi2 = mbase + j + 2; }
      if (d3 < bd3) { bd3 = d3; bi3 = mbase + j + 3; }
    }
    // exact first-occurrence merge across the 4 chains
    if (bd1 < bd0 || (bd1 == bd0 && bi1 < bi0)) { bd0 = bd1; bi0 = bi1; }
    if (bd3 < bd2 || (bd3 == bd2 && bi3 < bi2)) { bd2 = bd3; bi2 = bi3; }
    if (bd2 < bd0 || (bd2 == bd0 && bi2 < bi0)) { bd0 = bd2; bi0 = bi2; }
    unsigned long long key = ((unsigned long long)enc_f(bd0) << 32) | (unsigned)bi0;
    atomicMin(&best1[(size_t)b * N + n], key);
  } else {
    float bda = FLTMAX, bdb = FLTMAX;
    #pragma unroll 2
    for (int j = 0; j < 512; j += 4) {
      float4 t0 = other[j], t1 = other[j + 1], t2 = other[j + 2], t3 = other[j + 3];
      float d0 = fmaf(qx, t0.x, fmaf(qy, t0.y, fmaf(qz, t0.z, pp + t0.w)));
      float d1 = fmaf(qx, t1.x, fmaf(qy, t1.y, fmaf(qz, t1.z, pp + t1.w)));
      float d2 = fmaf(qx, t2.x, fmaf(qy, t2.y, fmaf(qz, t2.z, pp + t2.w)));
      float d3 = fmaf(qx, t3.x, fmaf(qy, t3.y, fmaf(qz, t3.z, pp + t3.w)));
      bda = fminf(fminf(d0, d1), bda);   // -> v_min3
      bdb = fminf(fminf(d2, d3), bdb);
    }
    atomicMin(&best2[(size_t)b * N + n], enc_f(fminf(bda, bdb)));
  }
}

// K4: finalize. Row sums + normal loss; last block (atomic ticket) folds edge
// partials and writes the scalar output.
__global__ __launch_bounds__(256) void finalize_kernel(
    const unsigned long long* __restrict__ best1, const unsigned* __restrict__ best2,
    const float4* __restrict__ pn4, const float4* __restrict__ gn4,
    const float* __restrict__ edgep,
    float* __restrict__ acc, unsigned* __restrict__ cnt, float* __restrict__ out) {
  __shared__ float s4[4];
  __shared__ unsigned ticket;
  int i = blockIdx.x * 256 + threadIdx.x;
  int b = i >> 12;
  unsigned long long k1 = best1[i];
  float d1 = dec_f((unsigned)(k1 >> 32));
  int m = (int)(unsigned)(k1 & 0xFFFFFFFFull);
  float d2 = dec_f(best2[i]);
  float4 a = pn4[i];
  float4 g = gn4[((size_t)b << 12) + m];
  float nl = 1.f - fabsf(a.x * g.x + a.y * g.y + a.z * g.z);
  float sd = block_sum_256(d1 + d2, s4);
  float sn = block_sum_256(nl, s4);
  if (threadIdx.x == 0) {
    atomicAdd(&acc[0], sd);
    atomicAdd(&acc[1], sn);
    __threadfence();
    ticket = atomicAdd(cnt, 1u);
  }
  __syncthreads();
  if (ticket == 127) {                     // last of 128 blocks
    float e = (threadIdx.x < SCAN_BLOCKS) ? edgep[threadIdx.x] : 0.f;
    float te = block_sum_256(e, s4);
    if (threadIdx.x == 0) {
      float chamf = atomicAdd(&acc[0], 0.f);   // coherent read of final value
      float nsum  = atomicAdd(&acc[1], 0.f);
      float inv_bn = 1.f / (float)BN;
      out[0] = chamf * inv_bn + 0.1f * (nsum * inv_bn) + 0.5f * (te / (3.f * (float)BF));
    }
  }
}

extern "C" void kernel_launch(void* const* d_in, const int* in_sizes, int n_in,
                              void* d_out, int out_size, void* d_ws, size_t ws_size,
                              hipStream_t stream) {
  const float* pv = (const float*)d_in[0];   // predicted_vertices [B,V,3]
  const int*   pf = (const int*)d_in[1];     // predicted_faces [F,3]
  // d_in[2]/d_in[3] (gt mesh) are unused by the reference.
  const float* rp = (const float*)d_in[4];   // rand_pred [B,N,3]
  const float* rg = (const float*)d_in[5];   // rand_gt   [B,N,3]
  float* out = (float*)d_out;

  // ws layout (16B-aligned float4 sections)
  unsigned long long* best1 = (unsigned long long*)d_ws;   // BN u64
  unsigned* best2 = (unsigned*)(best1 + BN);               // BN u32
  float4* pc4  = (float4*)(best2 + BN);                    // BN
  float4* pn4  = pc4 + BN;                                 // BN
  float4* gc4  = pn4 + BN;                                 // BN
  float4* gn4  = gc4 + BN;                                 // BN
  float4* nrm4 = gn4 + BN;                                 // BF
  float* cdf   = (float*)(nrm4 + BF);                      // BF
  float* csum  = cdf + BF;                                 // 216
  float* edgep = csum + SCAN_BLOCKS;                       // 216
  float* acc   = edgep + SCAN_BLOCKS;                      // 2
  unsigned* cnt = (unsigned*)(acc + 2);                    // 1

  scan_faces_kernel<<<SCAN_BLOCKS, 256, 0, stream>>>(pv, pf, cdf, csum, nrm4, edgep,
                                                     best1, best2, acc, cnt);
  sample_kernel<<<(2 * BN) / 256, 256, 0, stream>>>(pv, pf, cdf, csum, nrm4,
                                                    rp, rg, pc4, pn4, gc4, gn4);
  chamfer_kernel<<<2048, 256, 0, stream>>>(pc4, gc4, best1, best2);
  finalize_kernel<<<BN / 256, 256, 0, stream>>>(best1, best2, pn4, gn4, edgep,
                                                acc, cnt, out);
}